// Round 12
// baseline (805.648 us; speedup 1.0000x reference)
//
#include <hip/hip_runtime.h>
#include <hip/hip_bf16.h>

// Problem sizes (fixed by reference)
#define N_NODES 50000
#define N_EDGES 800000
#define F_IN    128
#define HID     128
#define PROJ    512
#define N_CLS   32
#define N_GRAPHS 256
#define T_EMB   768
#define NB_SCAN ((N_NODES + 255) / 256)   // 196

typedef __attribute__((ext_vector_type(8))) short bf16x8;
typedef __attribute__((ext_vector_type(4))) float f32x4;

__device__ __forceinline__ float bf2f(unsigned short u) {
    unsigned v = ((unsigned)u) << 16;
    return __uint_as_float(v);
}
__device__ __forceinline__ unsigned short f2us(float v) {
    __hip_bfloat16 b = __float2bfloat16(v);
    union { __hip_bfloat16 b; unsigned short u; } c; c.b = b; return c.u;
}

// ---- degree histogram (int atomics over dst) ----
__global__ void k_deg(const int* __restrict__ ei, int* __restrict__ cnt, int nE) {
    int e = blockIdx.x * 256 + threadIdx.x;
    if (e < nE) atomicAdd(cnt + ei[nE + e], 1);
}

// ---- parallel scan pass 1 ----
__global__ __launch_bounds__(256) void k_scan1(const int* __restrict__ cnt,
    int* __restrict__ rowstart, float* __restrict__ dnorm, int* __restrict__ bsum)
{
    __shared__ int ps[256];
    int t = threadIdx.x;
    int i = blockIdx.x * 256 + t;
    int c = (i < N_NODES) ? cnt[i] : 0;
    if (i < N_NODES) dnorm[i] = rsqrtf((float)c + 1.0f);
    ps[t] = c;
    __syncthreads();
    for (int off = 1; off < 256; off <<= 1) {
        int v = (t >= off) ? ps[t - off] : 0;
        __syncthreads();
        ps[t] += v;
        __syncthreads();
    }
    if (i < N_NODES) rowstart[i] = ps[t] - c;
    if (t == 255) bsum[blockIdx.x] = ps[255];
}

// ---- scan pass 2 ----
__global__ __launch_bounds__(256) void k_scan2(int* __restrict__ bsum) {
    __shared__ int ps[256];
    int t = threadIdx.x;
    int v = (t < NB_SCAN) ? bsum[t] : 0;
    ps[t] = v;
    __syncthreads();
    for (int off = 1; off < 256; off <<= 1) {
        int u = (t >= off) ? ps[t - off] : 0;
        __syncthreads();
        ps[t] += u;
        __syncthreads();
    }
    if (t < NB_SCAN) bsum[t] = ps[t] - v;
}

// ---- scan pass 3 ----
__global__ __launch_bounds__(256) void k_scan3(int* __restrict__ rowstart,
                                               const int* __restrict__ bsum) {
    int i = blockIdx.x * 256 + threadIdx.x;
    if (i < N_NODES) rowstart[i] += bsum[blockIdx.x];
    if (i == 0) rowstart[N_NODES] = N_EDGES;
}

// ---- fill CSR src lists ----
__global__ void k_fill(const int* __restrict__ ei, const int* __restrict__ rowstart,
                       int* __restrict__ cursor, int* __restrict__ srcl, int nE) {
    int e = blockIdx.x * 256 + threadIdx.x;
    if (e >= nE) return;
    int s = ei[e];
    int d = ei[nE + e];
    int pos = rowstart[d] + atomicAdd(cursor + d, 1);
    srcl[pos] = s;
}

// ---- combined prep: weight transpose+bf16 and graph boundaries ----
__global__ void k_prep(const float* __restrict__ W, unsigned short* __restrict__ Wt,
                       const int* __restrict__ batch, int* __restrict__ gstart) {
    int t = blockIdx.x * 256 + threadIdx.x;
    if (t < 4 * 128 * 128) {
        int l = t >> 14;
        int k = (t >> 7) & 127;
        int n = t & 127;
        Wt[(size_t)l * 16384 + n * 128 + k] = f2us(W[(size_t)l * 16384 + k * 128 + n]);
    } else {
        int r = t - 4 * 128 * 128;
        if (r <= N_NODES) {
            int b  = (r < N_NODES) ? batch[r] : N_GRAPHS;
            int bp = (r > 0) ? batch[r - 1] : -1;
            for (int g = bp + 1; g <= b && g <= N_GRAPHS; g++) gstart[g] = r;
        }
    }
}

// ---- GCN matmul via bf16 MFMA; BN fold in-block; slice-layout ph output ----
// ph layout: ph[slice][node][32], slice = col/32, 4 slices of 3.2 MB each.
__global__ __launch_bounds__(256) void k_gcn_mm_mfma(const void* __restrict__ inp,
    const unsigned short* __restrict__ Wt,   // [128 n][128 k] bf16 (n-major)
    const float* __restrict__ stats, const float* __restrict__ bng,
    const float* __restrict__ bnb, const float* __restrict__ dnorm,
    unsigned short* __restrict__ ph, int n)
{
    __shared__ __align__(16) unsigned short As[64][136];
    __shared__ __align__(16) unsigned short Bs[128][136];
    __shared__ float scs[128], shs[128];
    int t = threadIdx.x;
    int row0 = blockIdx.x * 64;

    if (stats) {
        if (t < 128) {
            float inv_n = 1.0f / (float)N_NODES;
            float mu = stats[t] * inv_n;
            float var = stats[128 + t] * inv_n - mu * mu;
            float rs = rsqrtf(var + 1e-5f);
            float sc = rs * bng[t];
            scs[t] = sc;
            shs[t] = bnb[t] - mu * sc;
        }
        __syncthreads();
    }

#pragma unroll
    for (int i = 0; i < 4; i++) {
        int c = t + i * 256;
        int r = c >> 4;
        int k8 = (c & 15) * 8;
        int gr = row0 + r;
        union { unsigned short u[8]; uint4 v; } pk;
        if (!stats) {
            const float* inf = (const float*)inp;
            float4 v0 = make_float4(0.f, 0.f, 0.f, 0.f);
            float4 v1 = make_float4(0.f, 0.f, 0.f, 0.f);
            if (gr < n) {
                v0 = *(const float4*)(inf + (size_t)gr * 128 + k8);
                v1 = *(const float4*)(inf + (size_t)gr * 128 + k8 + 4);
            }
            pk.u[0] = f2us(v0.x); pk.u[1] = f2us(v0.y); pk.u[2] = f2us(v0.z); pk.u[3] = f2us(v0.w);
            pk.u[4] = f2us(v1.x); pk.u[5] = f2us(v1.y); pk.u[6] = f2us(v1.z); pk.u[7] = f2us(v1.w);
        } else {
            const unsigned short* inb = (const unsigned short*)inp;
            uint4 raw = make_uint4(0, 0, 0, 0);
            if (gr < n) raw = *(const uint4*)(inb + (size_t)gr * 128 + k8);
            unsigned rr[4] = { raw.x, raw.y, raw.z, raw.w };
#pragma unroll
            for (int j = 0; j < 4; j++) {
                int f0 = k8 + 2 * j, f1 = k8 + 2 * j + 1;
                float a0 = bf2f((unsigned short)rr[j]) * scs[f0] + shs[f0];
                float a1 = bf2f((unsigned short)(rr[j] >> 16)) * scs[f1] + shs[f1];
                pk.u[2 * j] = f2us(a0);
                pk.u[2 * j + 1] = f2us(a1);
            }
        }
        *(uint4*)&As[r][k8] = pk.v;
    }
#pragma unroll
    for (int i = 0; i < 8; i++) {
        int c = t + i * 256;
        int nn = c >> 4;
        int k8 = (c & 15) * 8;
        *(uint4*)&Bs[nn][k8] = *(const uint4*)(Wt + (size_t)nn * 128 + k8);
    }
    __syncthreads();

    int w = t >> 6, lane = t & 63;
    int m = lane & 15, quad = lane >> 4;
    int arow = w * 16 + m;
    f32x4 acc[8];
#pragma unroll
    for (int nt = 0; nt < 8; nt++) acc[nt] = (f32x4){0.f, 0.f, 0.f, 0.f};

#pragma unroll
    for (int ki = 0; ki < 4; ki++) {
        bf16x8 a = *(const bf16x8*)&As[arow][ki * 32 + quad * 8];
#pragma unroll
        for (int nt = 0; nt < 8; nt++) {
            bf16x8 b = *(const bf16x8*)&Bs[nt * 16 + m][ki * 32 + quad * 8];
            acc[nt] = __builtin_amdgcn_mfma_f32_16x16x32_bf16(a, b, acc[nt], 0, 0, 0);
        }
    }

    float dn[4];
#pragma unroll
    for (int reg = 0; reg < 4; reg++) {
        int gr = row0 + w * 16 + quad * 4 + reg;
        dn[reg] = (gr < n) ? dnorm[gr] : 0.f;
    }
#pragma unroll
    for (int nt = 0; nt < 8; nt++) {
        int sl = nt >> 1;
        int cc = (nt & 1) * 16 + m;
        unsigned short* base = ph + (size_t)sl * N_NODES * 32;
#pragma unroll
        for (int reg = 0; reg < 4; reg++) {
            int gr = row0 + w * 16 + quad * 4 + reg;
            if (gr < n) base[(size_t)gr * 32 + cc] = f2us(acc[nt][reg] * dn[reg]);
        }
    }
}

// ---- feature-sliced gather: 4 passes of 32 features; per-pass working set
// 3.2 MB fits each XCD's 4 MB L2. 8 lanes/edge x 8 B; wave64 = 8 edges/instr. ----
__global__ __launch_bounds__(256) void k_gather(const unsigned short* __restrict__ ph,
    const int* __restrict__ srcl, const int* __restrict__ rowstart,
    const float* __restrict__ dnorm, const float* __restrict__ bias,
    unsigned short* __restrict__ outbb, float* __restrict__ stats, int n)
{
    const int EMAX = N_EDGES - 1;
    int t = threadIdx.x;
    int lane = t & 63;
    int w = t >> 6;
    int q = lane >> 3;        // edge group 0..7
    int l8 = lane & 7;        // feature chunk within slice
    __shared__ float sb[4][8][4], sq[4][8][4];

    for (int sl = 0; sl < 4; sl++) {
        const unsigned short* tab = ph + (size_t)sl * N_NODES * 32;
        int fb = sl * 32 + l8 * 4;
        float4 bi = *(const float4*)&bias[fb];
        float s0 = 0.f, s1 = 0.f, s2 = 0.f, s3 = 0.f;
        float q0 = 0.f, q1 = 0.f, q2 = 0.f, q3 = 0.f;

        for (int r = blockIdx.x * 4 + w; r < n; r += gridDim.x * 4) {
            int start = rowstart[r], end = rowstart[r + 1];
            int deg = end - start;
            int len = deg + 1;        // + self loop
            float a0 = 0.f, a1 = 0.f, a2 = 0.f, a3 = 0.f;
            int j = 0;
            for (; 8 * (j + 2) <= len; j += 2) {
#pragma unroll
                for (int u = 0; u < 2; u++) {
                    int i = 8 * (j + u) + q;
                    int s = srcl[min(start + i, EMAX)];
                    s = (i < deg) ? s : r;
                    uint2 uv = *(const uint2*)(tab + (size_t)s * 32 + l8 * 4);
                    a0 += bf2f((unsigned short)uv.x);
                    a1 += bf2f((unsigned short)(uv.x >> 16));
                    a2 += bf2f((unsigned short)uv.y);
                    a3 += bf2f((unsigned short)(uv.y >> 16));
                }
            }
            for (; 8 * j < len; j++) {
                int i = 8 * j + q;
                int s = srcl[min(start + i, EMAX)];
                s = (i < deg) ? s : r;
                uint2 uv = *(const uint2*)(tab + (size_t)s * 32 + l8 * 4);
                float w0 = (i < len) ? 1.f : 0.f;
                a0 += w0 * bf2f((unsigned short)uv.x);
                a1 += w0 * bf2f((unsigned short)(uv.x >> 16));
                a2 += w0 * bf2f((unsigned short)uv.y);
                a3 += w0 * bf2f((unsigned short)(uv.y >> 16));
            }
            // combine the 8 edge groups (lane bits 3,4,5)
            a0 += __shfl_xor(a0, 8, 64);  a1 += __shfl_xor(a1, 8, 64);
            a2 += __shfl_xor(a2, 8, 64);  a3 += __shfl_xor(a3, 8, 64);
            a0 += __shfl_xor(a0, 16, 64); a1 += __shfl_xor(a1, 16, 64);
            a2 += __shfl_xor(a2, 16, 64); a3 += __shfl_xor(a3, 16, 64);
            a0 += __shfl_xor(a0, 32, 64); a1 += __shfl_xor(a1, 32, 64);
            a2 += __shfl_xor(a2, 32, 64); a3 += __shfl_xor(a3, 32, 64);
            if (q == 0) {
                float dn = dnorm[r];
                float v0 = a0 * dn + bi.x;
                float v1 = a1 * dn + bi.y;
                float v2 = a2 * dn + bi.z;
                float v3 = a3 * dn + bi.w;
                v0 = v0 > 0.f ? v0 : 0.01f * v0;
                v1 = v1 > 0.f ? v1 : 0.01f * v1;
                v2 = v2 > 0.f ? v2 : 0.01f * v2;
                v3 = v3 > 0.f ? v3 : 0.01f * v3;
                ushort4 ov;
                ov.x = f2us(v0); ov.y = f2us(v1); ov.z = f2us(v2); ov.w = f2us(v3);
                *(ushort4*)(outbb + (size_t)r * 128 + fb) = ov;
                s0 += v0; s1 += v1; s2 += v2; s3 += v3;
                q0 += v0 * v0; q1 += v1 * v1; q2 += v2 * v2; q3 += v3 * v3;
            }
        }
        // per-pass block stats reduction
        if (q == 0) {
            sb[w][l8][0] = s0; sb[w][l8][1] = s1; sb[w][l8][2] = s2; sb[w][l8][3] = s3;
            sq[w][l8][0] = q0; sq[w][l8][1] = q1; sq[w][l8][2] = q2; sq[w][l8][3] = q3;
        }
        __syncthreads();
        if (t < 32) {
            int l = t >> 2, k = t & 3;
            float ss = (sb[0][l][k] + sb[1][l][k]) + (sb[2][l][k] + sb[3][l][k]);
            float qq = (sq[0][l][k] + sq[1][l][k]) + (sq[2][l][k] + sq[3][l][k]);
            atomicAdd(&stats[sl * 32 + l * 4 + k], ss);
            atomicAdd(&stats[128 + sl * 32 + l * 4 + k], qq);
        }
        __syncthreads();
    }
}

// ---- segmented mean pool (bf16 input); BN scale/shift computed in-block ----
__global__ __launch_bounds__(256) void k_pool2(const unsigned short* __restrict__ outbb,
    const int* __restrict__ gstart, const float* __restrict__ stats,
    const float* __restrict__ bng, const float* __restrict__ bnb,
    float* __restrict__ gemb)
{
    __shared__ float scs[128], shs[128];
    int g = blockIdx.x;
    int t = threadIdx.x;
    if (t < 128) {
        float inv_n = 1.0f / (float)N_NODES;
        float mu = stats[t] * inv_n;
        float var = stats[128 + t] * inv_n - mu * mu;
        float rs = rsqrtf(var + 1e-5f);
        float sc = rs * bng[t];
        scs[t] = sc;
        shs[t] = bnb[t] - mu * sc;
    }
    __syncthreads();
    int f = t & 127;
    int half = t >> 7;
    int start = gstart[g], end = gstart[g + 1];
    int cnt = end - start;
    float s0 = 0.f, s1 = 0.f, s2 = 0.f, s3 = 0.f;
    int r = start + half;
    for (; r + 6 < end; r += 8) {
        s0 += bf2f(outbb[(size_t)(r    ) * 128 + f]);
        s1 += bf2f(outbb[(size_t)(r + 2) * 128 + f]);
        s2 += bf2f(outbb[(size_t)(r + 4) * 128 + f]);
        s3 += bf2f(outbb[(size_t)(r + 6) * 128 + f]);
    }
    for (; r < end; r += 2) s0 += bf2f(outbb[(size_t)r * 128 + f]);
    float sum = (s0 + s1) + (s2 + s3);
    __shared__ float sb[256];
    sb[t] = sum;
    __syncthreads();
    if (t < 128) {
        float tot = sb[t] + sb[t + 128];
        float v = (cnt > 0) ? (tot / (float)cnt) * scs[f] + shs[f] : 0.f;
        gemb[(size_t)g * 128 + f] = v;
    }
}

// ---- fused head layer 1 for both heads ----
__global__ __launch_bounds__(256) void k_head1x(const float* __restrict__ gemb,
    const float* __restrict__ textf,
    const float* __restrict__ gW1, const float* __restrict__ gb1,
    const float* __restrict__ tW1, const float* __restrict__ tb1,
    float* __restrict__ projg, float* __restrict__ projt)
{
    __shared__ float ins[8][768];
    int bx = blockIdx.x;
    int chunk = blockIdx.y;
    int isT = bx >= 32;
    int rb = isT ? bx - 32 : bx;
    const float* in = isT ? textf : gemb;
    int K = isT ? T_EMB : HID;
    const float* W = isT ? tW1 : gW1;
    const float* b = isT ? tb1 : gb1;
    float* outp = isT ? projt : projg;

    int t = threadIdx.x;
    int tot = 8 * K;
    for (int l = t; l < tot; l += 256) {
        int r = l / K, k = l - r * K;
        ins[r][k] = in[(size_t)(rb * 8 + r) * K + k];
    }
    __syncthreads();
    int col = chunk * 128 + (t & 127);
    int rg = t >> 7;
    float acc[4] = { 0.f, 0.f, 0.f, 0.f };
    for (int k = 0; k < K; k++) {
        float w = W[(size_t)k * 512 + col];
#pragma unroll
        for (int i = 0; i < 4; i++) acc[i] += ins[rg * 4 + i][k] * w;
    }
    float bias = b[col];
#pragma unroll
    for (int i = 0; i < 4; i++) {
        int row = rb * 8 + rg * 4 + i;
        outp[(size_t)row * 512 + col] = acc[i] + bias;
    }
}

// ---- fused head2 + LayerNorm + classifier + log_softmax, both heads ----
__global__ __launch_bounds__(256) void k_head2c(
    const float* __restrict__ projg, const float* __restrict__ projt,
    const float* __restrict__ gW2, const float* __restrict__ gb2,
    const float* __restrict__ gg, const float* __restrict__ gbe,
    const float* __restrict__ gclW, const float* __restrict__ gclb,
    const float* __restrict__ tW2, const float* __restrict__ tb2,
    const float* __restrict__ tg, const float* __restrict__ tbe,
    const float* __restrict__ tclW, const float* __restrict__ tclb,
    float* __restrict__ o_gproj, float* __restrict__ o_tproj,
    float* __restrict__ o_glogp, float* __restrict__ o_tlogp)
{
    __shared__ float prow[512], grow[512], onorm[512], red[256];
    __shared__ float part[8][32];
    __shared__ float logits[32];
    __shared__ float mred, lred;
    int bx = blockIdx.x;
    int isT = bx >= N_GRAPHS;
    int row = isT ? bx - N_GRAPHS : bx;
    const float* proj = isT ? projt : projg;
    const float* W2 = isT ? tW2 : gW2;
    const float* b2 = isT ? tb2 : gb2;
    const float* g  = isT ? tg  : gg;
    const float* be = isT ? tbe : gbe;
    const float* Wc = isT ? tclW : gclW;
    const float* bc = isT ? tclb : gclb;
    float* oproj = isT ? o_tproj : o_gproj;
    float* ologp = isT ? o_tlogp : o_glogp;

    int t = threadIdx.x;
    for (int c = t; c < 512; c += 256) {
        float p = proj[(size_t)row * 512 + c];
        prow[c] = p;
        grow[c] = 0.5f * p * (1.0f + erff(p * 0.70710678118f));
    }
    __syncthreads();
    float a0 = 0.f, a1 = 0.f;
    int c0 = t, c1 = t + 256;
    for (int k = 0; k < 512; k++) {
        float gk = grow[k];
        a0 += gk * W2[(size_t)k * 512 + c0];
        a1 += gk * W2[(size_t)k * 512 + c1];
    }
    float h0 = a0 + b2[c0] + prow[c0];
    float h1 = a1 + b2[c1] + prow[c1];
    red[t] = h0 + h1;
    __syncthreads();
    for (int s = 128; s > 0; s >>= 1) { if (t < s) red[t] += red[t + s]; __syncthreads(); }
    float mu = red[0] * (1.0f / 512.0f);
    __syncthreads();
    float d0 = h0 - mu, d1 = h1 - mu;
    red[t] = d0 * d0 + d1 * d1;
    __syncthreads();
    for (int s = 128; s > 0; s >>= 1) { if (t < s) red[t] += red[t + s]; __syncthreads(); }
    float rs = rsqrtf(red[0] * (1.0f / 512.0f) + 1e-5f);
    float o0 = d0 * rs * g[c0] + be[c0];
    float o1 = d1 * rs * g[c1] + be[c1];
    onorm[c0] = o0;
    onorm[c1] = o1;
    oproj[(size_t)row * 512 + c0] = o0;
    oproj[(size_t)row * 512 + c1] = o1;
    __syncthreads();

    int c = t & 31, seg = t >> 5;
    float p = 0.f;
    for (int k = seg * 64; k < seg * 64 + 64; k++)
        p += onorm[k] * Wc[(size_t)k * 32 + c];
    part[seg][c] = p;
    __syncthreads();
    if (t < 32) {
        float l = bc[t];
#pragma unroll
        for (int s = 0; s < 8; s++) l += part[s][t];
        logits[t] = l;
    }
    __syncthreads();
    if (t == 0) {
        float m = logits[0];
        for (int i = 1; i < 32; i++) m = fmaxf(m, logits[i]);
        float sum = 0.f;
        for (int i = 0; i < 32; i++) sum += expf(logits[i] - m);
        mred = m; lred = logf(sum);
    }
    __syncthreads();
    if (t < 32) ologp[(size_t)row * 32 + t] = logits[t] - mred - lred;
}

extern "C" void kernel_launch(void* const* d_in, const int* in_sizes, int n_in,
                              void* d_out, int out_size, void* d_ws, size_t ws_size,
                              hipStream_t stream) {
    const float* x     = (const float*)d_in[0];
    const int*   ei    = (const int*)d_in[1];
    const int*   batch = (const int*)d_in[2];
    const float* textf = (const float*)d_in[3];
    const float* gcnW  = (const float*)d_in[4];
    const float* gcnb  = (const float*)d_in[5];
    const float* bng   = (const float*)d_in[6];
    const float* bnb   = (const float*)d_in[7];
    const float* gW1   = (const float*)d_in[8];
    const float* gb1   = (const float*)d_in[9];
    const float* gW2   = (const float*)d_in[10];
    const float* gb2   = (const float*)d_in[11];
    const float* gg    = (const float*)d_in[12];
    const float* gbe   = (const float*)d_in[13];
    const float* gclW  = (const float*)d_in[14];
    const float* gclb  = (const float*)d_in[15];
    const float* tW1   = (const float*)d_in[16];
    const float* tb1   = (const float*)d_in[17];
    const float* tW2   = (const float*)d_in[18];
    const float* tb2   = (const float*)d_in[19];
    const float* tg    = (const float*)d_in[20];
    const float* tbe   = (const float*)d_in[21];
    const float* tclW  = (const float*)d_in[22];
    const float* tclb  = (const float*)d_in[23];

    const int N = N_NODES, E = N_EDGES;
    const int NF = N * HID;

    float* p = (float*)d_ws;
    unsigned short* outbb = (unsigned short*)p; p += NF / 2;   // 12.8 MB bf16
    unsigned short* ph    = (unsigned short*)p; p += NF / 2;   // 12.8 MB bf16, 4 slices
    unsigned short* Wt    = (unsigned short*)p; p += 4 * 16384 / 2;
    float* dnorm = p; p += N;
    float* gemb  = p; p += N_GRAPHS * HID;
    float* projg = p; p += N_GRAPHS * PROJ;
    float* projt = p; p += N_GRAPHS * PROJ;
    // contiguous zero-init region: cnt | cursor | stats4
    int* cnt      = (int*)p; p += N;
    int* cursor   = (int*)p; p += N;
    float* stats4 = p; p += 4 * 256;
    int* rowstart = (int*)p; p += N + 1;
    int* gstart   = (int*)p; p += N_GRAPHS + 1;
    int* bsum     = (int*)p; p += 256;
    int* srcl     = (int*)p; p += E;

    float* outp = (float*)d_out;
    float* o_gproj = outp;
    float* o_tproj = outp + N_GRAPHS * PROJ;
    float* o_glogp = o_tproj + N_GRAPHS * PROJ;
    float* o_tlogp = o_glogp + N_GRAPHS * N_CLS;

    // ---- CSR build + prep ----
    hipMemsetAsync(cnt, 0, (size_t)(2 * N + 4 * 256) * sizeof(int), stream);
    k_deg<<<(E + 255) / 256, 256, 0, stream>>>(ei, cnt, E);
    k_scan1<<<NB_SCAN, 256, 0, stream>>>(cnt, rowstart, dnorm, bsum);
    k_scan2<<<1, 256, 0, stream>>>(bsum);
    k_scan3<<<NB_SCAN, 256, 0, stream>>>(rowstart, bsum);
    k_fill<<<(E + 255) / 256, 256, 0, stream>>>(ei, rowstart, cursor, srcl, E);
    k_prep<<<(4 * 16384 + N + 1 + 255) / 256, 256, 0, stream>>>(gcnW, Wt, batch, gstart);

    // ---- 4 GCN layers (BN of layer l-1 folded into mm of layer l) ----
    for (int l = 0; l < 4; l++) {
        const void* in = (l == 0) ? (const void*)x : (const void*)outbb;
        const float* st = (l == 0) ? nullptr : stats4 + (l - 1) * 256;
        const float* bg = (l == 0) ? nullptr : bng + (size_t)(l - 1) * HID;
        const float* bb = (l == 0) ? nullptr : bnb + (size_t)(l - 1) * HID;
        k_gcn_mm_mfma<<<(N + 63) / 64, 256, 0, stream>>>(in, Wt + (size_t)l * 16384,
                                                         st, bg, bb, dnorm, ph, N);
        k_gather<<<2048, 256, 0, stream>>>(ph, srcl, rowstart, dnorm,
                                           gcnb + (size_t)l * HID, outbb,
                                           stats4 + l * 256, N);
    }

    // ---- segmented mean pool (layer-3 BN folded in-block) ----
    k_pool2<<<N_GRAPHS, 256, 0, stream>>>(outbb, gstart, stats4 + 3 * 256,
                                          bng + 3 * HID, bnb + 3 * HID, gemb);

    // ---- fused heads ----
    k_head1x<<<dim3(64, 4), 256, 0, stream>>>(gemb, textf, gW1, gb1, tW1, tb1, projg, projt);
    k_head2c<<<2 * N_GRAPHS, 256, 0, stream>>>(projg, projt,
                                               gW2, gb2, gg, gbe, gclW, gclb,
                                               tW2, tb2, tg, tbe, tclW, tclb,
                                               o_gproj, o_tproj, o_glogp, o_tlogp);
}

// Round 14
// 649.358 us; speedup vs baseline: 1.2407x; 1.2407x over previous
//
#include <hip/hip_runtime.h>
#include <hip/hip_bf16.h>

// Problem sizes (fixed by reference)
#define N_NODES 50000
#define N_EDGES 800000
#define F_IN    128
#define HID     128
#define PROJ    512
#define N_CLS   32
#define N_GRAPHS 256
#define T_EMB   768
#define NB_SCAN ((N_NODES + 255) / 256)   // 196

typedef __attribute__((ext_vector_type(8))) short bf16x8;
typedef __attribute__((ext_vector_type(4))) float f32x4;

__device__ __forceinline__ float bf2f(unsigned short u) {
    unsigned v = ((unsigned)u) << 16;
    return __uint_as_float(v);
}
__device__ __forceinline__ unsigned short f2us(float v) {
    __hip_bfloat16 b = __float2bfloat16(v);
    union { __hip_bfloat16 b; unsigned short u; } c; c.b = b; return c.u;
}

// ---- degree histogram (int atomics over dst) ----
__global__ void k_deg(const int* __restrict__ ei, int* __restrict__ cnt, int nE) {
    int e = blockIdx.x * 256 + threadIdx.x;
    if (e < nE) atomicAdd(cnt + ei[nE + e], 1);
}

// ---- parallel scan pass 1 ----
__global__ __launch_bounds__(256) void k_scan1(const int* __restrict__ cnt,
    int* __restrict__ rowstart, float* __restrict__ dnorm, int* __restrict__ bsum)
{
    __shared__ int ps[256];
    int t = threadIdx.x;
    int i = blockIdx.x * 256 + t;
    int c = (i < N_NODES) ? cnt[i] : 0;
    if (i < N_NODES) dnorm[i] = rsqrtf((float)c + 1.0f);
    ps[t] = c;
    __syncthreads();
    for (int off = 1; off < 256; off <<= 1) {
        int v = (t >= off) ? ps[t - off] : 0;
        __syncthreads();
        ps[t] += v;
        __syncthreads();
    }
    if (i < N_NODES) rowstart[i] = ps[t] - c;
    if (t == 255) bsum[blockIdx.x] = ps[255];
}

// ---- scan pass 2 ----
__global__ __launch_bounds__(256) void k_scan2(int* __restrict__ bsum) {
    __shared__ int ps[256];
    int t = threadIdx.x;
    int v = (t < NB_SCAN) ? bsum[t] : 0;
    ps[t] = v;
    __syncthreads();
    for (int off = 1; off < 256; off <<= 1) {
        int u = (t >= off) ? ps[t - off] : 0;
        __syncthreads();
        ps[t] += u;
        __syncthreads();
    }
    if (t < NB_SCAN) bsum[t] = ps[t] - v;
}

// ---- scan pass 3 ----
__global__ __launch_bounds__(256) void k_scan3(int* __restrict__ rowstart,
                                               const int* __restrict__ bsum) {
    int i = blockIdx.x * 256 + threadIdx.x;
    if (i < N_NODES) rowstart[i] += bsum[blockIdx.x];
    if (i == 0) rowstart[N_NODES] = N_EDGES;
}

// ---- fill CSR src lists ----
__global__ void k_fill(const int* __restrict__ ei, const int* __restrict__ rowstart,
                       int* __restrict__ cursor, int* __restrict__ srcl, int nE) {
    int e = blockIdx.x * 256 + threadIdx.x;
    if (e >= nE) return;
    int s = ei[e];
    int d = ei[nE + e];
    int pos = rowstart[d] + atomicAdd(cursor + d, 1);
    srcl[pos] = s;
}

// ---- combined prep: weight transpose+bf16 and graph boundaries ----
__global__ void k_prep(const float* __restrict__ W, unsigned short* __restrict__ Wt,
                       const int* __restrict__ batch, int* __restrict__ gstart) {
    int t = blockIdx.x * 256 + threadIdx.x;
    if (t < 4 * 128 * 128) {
        int l = t >> 14;
        int k = (t >> 7) & 127;
        int n = t & 127;
        Wt[(size_t)l * 16384 + n * 128 + k] = f2us(W[(size_t)l * 16384 + k * 128 + n]);
    } else {
        int r = t - 4 * 128 * 128;
        if (r <= N_NODES) {
            int b  = (r < N_NODES) ? batch[r] : N_GRAPHS;
            int bp = (r > 0) ? batch[r - 1] : -1;
            for (int g = bp + 1; g <= b && g <= N_GRAPHS; g++) gstart[g] = r;
        }
    }
}

// ---- GCN matmul via bf16 MFMA; A-fragments loaded DIRECTLY from global
// (no LDS A-stage: LDS = Bs only -> 4 blocks/CU, 16 waves/CU, 1 barrier).
// BN fold in-register; ph row-major, dnorm[row] folded in epilogue. ----
__global__ __launch_bounds__(256) void k_gcn_mm_mfma(const void* __restrict__ inp,
    const unsigned short* __restrict__ Wt,   // [128 n][128 k] bf16 (n-major)
    const float* __restrict__ stats, const float* __restrict__ bng,
    const float* __restrict__ bnb, const float* __restrict__ dnorm,
    unsigned short* __restrict__ ph, int n)
{
    __shared__ __align__(16) unsigned short Bs[128][136];   // 34.8 KB
    __shared__ float scs[128], shs[128];
    int t = threadIdx.x;
    int row0 = blockIdx.x * 64;

    if (stats && t < 128) {
        float inv_n = 1.0f / (float)N_NODES;
        float mu = stats[t] * inv_n;
        float var = stats[128 + t] * inv_n - mu * mu;
        float rs = rsqrtf(var + 1e-5f);
        float sc = rs * bng[t];
        scs[t] = sc;
        shs[t] = bnb[t] - mu * sc;
    }
#pragma unroll
    for (int i = 0; i < 8; i++) {
        int c = t + i * 256;
        int nn = c >> 4;
        int k8 = (c & 15) * 8;
        *(uint4*)&Bs[nn][k8] = *(const uint4*)(Wt + (size_t)nn * 128 + k8);
    }
    __syncthreads();

    int w = t >> 6, lane = t & 63;
    int m = lane & 15, quad = lane >> 4;
    int arow = row0 + w * 16 + m;        // this lane's A row
    bool rowok = arow < n;

    // load A fragments for all 4 k-chunks (16 B each, aligned)
    bf16x8 afrag[4];
    if (!stats) {
        const float* inf = (const float*)inp;
#pragma unroll
        for (int ki = 0; ki < 4; ki++) {
            int k8 = ki * 32 + quad * 8;
            float4 v0 = make_float4(0.f, 0.f, 0.f, 0.f);
            float4 v1 = make_float4(0.f, 0.f, 0.f, 0.f);
            if (rowok) {
                v0 = *(const float4*)(inf + (size_t)arow * 128 + k8);
                v1 = *(const float4*)(inf + (size_t)arow * 128 + k8 + 4);
            }
            union { unsigned short u[8]; bf16x8 v; } pk;
            pk.u[0] = f2us(v0.x); pk.u[1] = f2us(v0.y); pk.u[2] = f2us(v0.z); pk.u[3] = f2us(v0.w);
            pk.u[4] = f2us(v1.x); pk.u[5] = f2us(v1.y); pk.u[6] = f2us(v1.z); pk.u[7] = f2us(v1.w);
            afrag[ki] = pk.v;
        }
    } else {
        const unsigned short* inb = (const unsigned short*)inp;
#pragma unroll
        for (int ki = 0; ki < 4; ki++) {
            int k8 = ki * 32 + quad * 8;
            uint4 raw = make_uint4(0, 0, 0, 0);
            if (rowok) raw = *(const uint4*)(inb + (size_t)arow * 128 + k8);
            unsigned rr[4] = { raw.x, raw.y, raw.z, raw.w };
            union { unsigned short u[8]; bf16x8 v; } pk;
#pragma unroll
            for (int j = 0; j < 4; j++) {
                int f0 = k8 + 2 * j, f1 = k8 + 2 * j + 1;
                float a0 = bf2f((unsigned short)rr[j]) * scs[f0] + shs[f0];
                float a1 = bf2f((unsigned short)(rr[j] >> 16)) * scs[f1] + shs[f1];
                pk.u[2 * j] = f2us(a0);
                pk.u[2 * j + 1] = f2us(a1);
            }
            afrag[ki] = pk.v;
        }
    }

    f32x4 acc[8];
#pragma unroll
    for (int nt = 0; nt < 8; nt++) acc[nt] = (f32x4){0.f, 0.f, 0.f, 0.f};
#pragma unroll
    for (int ki = 0; ki < 4; ki++) {
#pragma unroll
        for (int nt = 0; nt < 8; nt++) {
            bf16x8 b = *(const bf16x8*)&Bs[nt * 16 + m][ki * 32 + quad * 8];
            acc[nt] = __builtin_amdgcn_mfma_f32_16x16x32_bf16(afrag[ki], b, acc[nt], 0, 0, 0);
        }
    }

    float dn[4];
#pragma unroll
    for (int reg = 0; reg < 4; reg++) {
        int gr = row0 + w * 16 + quad * 4 + reg;
        dn[reg] = (gr < n) ? dnorm[gr] : 0.f;
    }
#pragma unroll
    for (int nt = 0; nt < 8; nt++) {
#pragma unroll
        for (int reg = 0; reg < 4; reg++) {
            int gr = row0 + w * 16 + quad * 4 + reg;
            int col = nt * 16 + m;
            if (gr < n) ph[(size_t)gr * 128 + col] = f2us(acc[nt][reg] * dn[reg]);
        }
    }
}

// ---- pair-gather (round-11 form): one wave per dst row; bf16 output ----
__global__ __launch_bounds__(256) void k_gather(const unsigned long long* __restrict__ ph64,
    const int* __restrict__ srcl, const int* __restrict__ rowstart,
    const float* __restrict__ dnorm, const float* __restrict__ bias,
    unsigned short* __restrict__ outbb, float* __restrict__ stats, int n)
{
    const int EMAX = N_EDGES - 1;
    int t = threadIdx.x;
    int lane = t & 63;
    int w = t >> 6;
    int hl = lane >> 5;
    int l32 = lane & 31;
    float4 bi4 = *(const float4*)&bias[l32 * 4];
    float4 s4 = make_float4(0.f, 0.f, 0.f, 0.f);
    float4 q4 = make_float4(0.f, 0.f, 0.f, 0.f);

    for (int r = blockIdx.x * 4 + w; r < n; r += gridDim.x * 4) {
        int start = rowstart[r], end = rowstart[r + 1];
        int deg = end - start;
        int len = deg + 1;
        float a0 = 0.f, a1 = 0.f, a2 = 0.f, a3 = 0.f;
        int j = 0;
        for (; 2 * (j + 4) <= len; j += 4) {
#pragma unroll
            for (int u = 0; u < 4; u++) {
                int i = 2 * (j + u) + hl;
                int sl = srcl[min(start + i, EMAX)];
                int s = (i < deg) ? sl : r;
                unsigned long long uv = ph64[(size_t)s * 32 + l32];
                unsigned lo = (unsigned)uv, hi = (unsigned)(uv >> 32);
                a0 += bf2f((unsigned short)lo);
                a1 += bf2f((unsigned short)(lo >> 16));
                a2 += bf2f((unsigned short)hi);
                a3 += bf2f((unsigned short)(hi >> 16));
            }
        }
        for (; 2 * j < len; j++) {
            int i = 2 * j + hl;
            int sl = srcl[min(start + i, EMAX)];
            int s = (i < deg) ? sl : r;
            unsigned long long uv = ph64[(size_t)s * 32 + l32];
            float w0 = (i < len) ? 1.f : 0.f;
            unsigned lo = (unsigned)uv, hi = (unsigned)(uv >> 32);
            a0 += w0 * bf2f((unsigned short)lo);
            a1 += w0 * bf2f((unsigned short)(lo >> 16));
            a2 += w0 * bf2f((unsigned short)hi);
            a3 += w0 * bf2f((unsigned short)(hi >> 16));
        }
        a0 += __shfl_xor(a0, 32, 64);
        a1 += __shfl_xor(a1, 32, 64);
        a2 += __shfl_xor(a2, 32, 64);
        a3 += __shfl_xor(a3, 32, 64);
        if (hl == 0) {
            float dn = dnorm[r];
            float v0 = a0 * dn + bi4.x;
            float v1 = a1 * dn + bi4.y;
            float v2 = a2 * dn + bi4.z;
            float v3 = a3 * dn + bi4.w;
            v0 = v0 > 0.f ? v0 : 0.01f * v0;
            v1 = v1 > 0.f ? v1 : 0.01f * v1;
            v2 = v2 > 0.f ? v2 : 0.01f * v2;
            v3 = v3 > 0.f ? v3 : 0.01f * v3;
            ushort4 ov;
            ov.x = f2us(v0); ov.y = f2us(v1); ov.z = f2us(v2); ov.w = f2us(v3);
            *(ushort4*)(outbb + (size_t)r * 128 + l32 * 4) = ov;
            s4.x += v0; s4.y += v1; s4.z += v2; s4.w += v3;
            q4.x += v0 * v0; q4.y += v1 * v1; q4.z += v2 * v2; q4.w += v3 * v3;
        }
    }
    __shared__ float sb[4][32][4], sq[4][32][4];
    if (hl == 0) {
        *(float4*)&sb[w][l32][0] = s4;
        *(float4*)&sq[w][l32][0] = q4;
    }
    __syncthreads();
    if (t < 128) {
        int f = t, l = f >> 2, c = f & 3;
        float ss = (sb[0][l][c] + sb[1][l][c]) + (sb[2][l][c] + sb[3][l][c]);
        float qq = (sq[0][l][c] + sq[1][l][c]) + (sq[2][l][c] + sq[3][l][c]);
        atomicAdd(&stats[f], ss);
        atomicAdd(&stats[128 + f], qq);
    }
}

// ---- segmented mean pool (bf16 input); BN scale/shift computed in-block ----
__global__ __launch_bounds__(256) void k_pool2(const unsigned short* __restrict__ outbb,
    const int* __restrict__ gstart, const float* __restrict__ stats,
    const float* __restrict__ bng, const float* __restrict__ bnb,
    float* __restrict__ gemb)
{
    __shared__ float scs[128], shs[128];
    int g = blockIdx.x;
    int t = threadIdx.x;
    if (t < 128) {
        float inv_n = 1.0f / (float)N_NODES;
        float mu = stats[t] * inv_n;
        float var = stats[128 + t] * inv_n - mu * mu;
        float rs = rsqrtf(var + 1e-5f);
        float sc = rs * bng[t];
        scs[t] = sc;
        shs[t] = bnb[t] - mu * sc;
    }
    __syncthreads();
    int f = t & 127;
    int half = t >> 7;
    int start = gstart[g], end = gstart[g + 1];
    int cnt = end - start;
    float s0 = 0.f, s1 = 0.f, s2 = 0.f, s3 = 0.f;
    int r = start + half;
    for (; r + 6 < end; r += 8) {
        s0 += bf2f(outbb[(size_t)(r    ) * 128 + f]);
        s1 += bf2f(outbb[(size_t)(r + 2) * 128 + f]);
        s2 += bf2f(outbb[(size_t)(r + 4) * 128 + f]);
        s3 += bf2f(outbb[(size_t)(r + 6) * 128 + f]);
    }
    for (; r < end; r += 2) s0 += bf2f(outbb[(size_t)r * 128 + f]);
    float sum = (s0 + s1) + (s2 + s3);
    __shared__ float sb[256];
    sb[t] = sum;
    __syncthreads();
    if (t < 128) {
        float tot = sb[t] + sb[t + 128];
        float v = (cnt > 0) ? (tot / (float)cnt) * scs[f] + shs[f] : 0.f;
        gemb[(size_t)g * 128 + f] = v;
    }
}

// ---- fused head layer 1 for both heads ----
__global__ __launch_bounds__(256) void k_head1x(const float* __restrict__ gemb,
    const float* __restrict__ textf,
    const float* __restrict__ gW1, const float* __restrict__ gb1,
    const float* __restrict__ tW1, const float* __restrict__ tb1,
    float* __restrict__ projg, float* __restrict__ projt)
{
    __shared__ float ins[8][768];
    int bx = blockIdx.x;
    int chunk = blockIdx.y;
    int isT = bx >= 32;
    int rb = isT ? bx - 32 : bx;
    const float* in = isT ? textf : gemb;
    int K = isT ? T_EMB : HID;
    const float* W = isT ? tW1 : gW1;
    const float* b = isT ? tb1 : gb1;
    float* outp = isT ? projt : projg;

    int t = threadIdx.x;
    int tot = 8 * K;
    for (int l = t; l < tot; l += 256) {
        int r = l / K, k = l - r * K;
        ins[r][k] = in[(size_t)(rb * 8 + r) * K + k];
    }
    __syncthreads();
    int col = chunk * 128 + (t & 127);
    int rg = t >> 7;
    float acc[4] = { 0.f, 0.f, 0.f, 0.f };
    for (int k = 0; k < K; k++) {
        float w = W[(size_t)k * 512 + col];
#pragma unroll
        for (int i = 0; i < 4; i++) acc[i] += ins[rg * 4 + i][k] * w;
    }
    float bias = b[col];
#pragma unroll
    for (int i = 0; i < 4; i++) {
        int row = rb * 8 + rg * 4 + i;
        outp[(size_t)row * 512 + col] = acc[i] + bias;
    }
}

// ---- fused head2 + LayerNorm + classifier + log_softmax, both heads ----
__global__ __launch_bounds__(256) void k_head2c(
    const float* __restrict__ projg, const float* __restrict__ projt,
    const float* __restrict__ gW2, const float* __restrict__ gb2,
    const float* __restrict__ gg, const float* __restrict__ gbe,
    const float* __restrict__ gclW, const float* __restrict__ gclb,
    const float* __restrict__ tW2, const float* __restrict__ tb2,
    const float* __restrict__ tg, const float* __restrict__ tbe,
    const float* __restrict__ tclW, const float* __restrict__ tclb,
    float* __restrict__ o_gproj, float* __restrict__ o_tproj,
    float* __restrict__ o_glogp, float* __restrict__ o_tlogp)
{
    __shared__ float prow[512], grow[512], onorm[512], red[256];
    __shared__ float part[8][32];
    __shared__ float logits[32];
    __shared__ float mred, lred;
    int bx = blockIdx.x;
    int isT = bx >= N_GRAPHS;
    int row = isT ? bx - N_GRAPHS : bx;
    const float* proj = isT ? projt : projg;
    const float* W2 = isT ? tW2 : gW2;
    const float* b2 = isT ? tb2 : gb2;
    const float* g  = isT ? tg  : gg;
    const float* be = isT ? tbe : gbe;
    const float* Wc = isT ? tclW : gclW;
    const float* bc = isT ? tclb : gclb;
    float* oproj = isT ? o_tproj : o_gproj;
    float* ologp = isT ? o_tlogp : o_glogp;

    int t = threadIdx.x;
    for (int c = t; c < 512; c += 256) {
        float p = proj[(size_t)row * 512 + c];
        prow[c] = p;
        grow[c] = 0.5f * p * (1.0f + erff(p * 0.70710678118f));
    }
    __syncthreads();
    float a0 = 0.f, a1 = 0.f;
    int c0 = t, c1 = t + 256;
    for (int k = 0; k < 512; k++) {
        float gk = grow[k];
        a0 += gk * W2[(size_t)k * 512 + c0];
        a1 += gk * W2[(size_t)k * 512 + c1];
    }
    float h0 = a0 + b2[c0] + prow[c0];
    float h1 = a1 + b2[c1] + prow[c1];
    red[t] = h0 + h1;
    __syncthreads();
    for (int s = 128; s > 0; s >>= 1) { if (t < s) red[t] += red[t + s]; __syncthreads(); }
    float mu = red[0] * (1.0f / 512.0f);
    __syncthreads();
    float d0 = h0 - mu, d1 = h1 - mu;
    red[t] = d0 * d0 + d1 * d1;
    __syncthreads();
    for (int s = 128; s > 0; s >>= 1) { if (t < s) red[t] += red[t + s]; __syncthreads(); }
    float rs = rsqrtf(red[0] * (1.0f / 512.0f) + 1e-5f);
    float o0 = d0 * rs * g[c0] + be[c0];
    float o1 = d1 * rs * g[c1] + be[c1];
    onorm[c0] = o0;
    onorm[c1] = o1;
    oproj[(size_t)row * 512 + c0] = o0;
    oproj[(size_t)row * 512 + c1] = o1;
    __syncthreads();

    int c = t & 31, seg = t >> 5;
    float p = 0.f;
    for (int k = seg * 64; k < seg * 64 + 64; k++)
        p += onorm[k] * Wc[(size_t)k * 32 + c];
    part[seg][c] = p;
    __syncthreads();
    if (t < 32) {
        float l = bc[t];
#pragma unroll
        for (int s = 0; s < 8; s++) l += part[s][t];
        logits[t] = l;
    }
    __syncthreads();
    if (t == 0) {
        float m = logits[0];
        for (int i = 1; i < 32; i++) m = fmaxf(m, logits[i]);
        float sum = 0.f;
        for (int i = 0; i < 32; i++) sum += expf(logits[i] - m);
        mred = m; lred = logf(sum);
    }
    __syncthreads();
    if (t < 32) ologp[(size_t)row * 32 + t] = logits[t] - mred - lred;
}

extern "C" void kernel_launch(void* const* d_in, const int* in_sizes, int n_in,
                              void* d_out, int out_size, void* d_ws, size_t ws_size,
                              hipStream_t stream) {
    const float* x     = (const float*)d_in[0];
    const int*   ei    = (const int*)d_in[1];
    const int*   batch = (const int*)d_in[2];
    const float* textf = (const float*)d_in[3];
    const float* gcnW  = (const float*)d_in[4];
    const float* gcnb  = (const float*)d_in[5];
    const float* bng   = (const float*)d_in[6];
    const float* bnb   = (const float*)d_in[7];
    const float* gW1   = (const float*)d_in[8];
    const float* gb1   = (const float*)d_in[9];
    const float* gW2   = (const float*)d_in[10];
    const float* gb2   = (const float*)d_in[11];
    const float* gg    = (const float*)d_in[12];
    const float* gbe   = (const float*)d_in[13];
    const float* gclW  = (const float*)d_in[14];
    const float* gclb  = (const float*)d_in[15];
    const float* tW1   = (const float*)d_in[16];
    const float* tb1   = (const float*)d_in[17];
    const float* tW2   = (const float*)d_in[18];
    const float* tb2   = (const float*)d_in[19];
    const float* tg    = (const float*)d_in[20];
    const float* tbe   = (const float*)d_in[21];
    const float* tclW  = (const float*)d_in[22];
    const float* tclb  = (const float*)d_in[23];

    const int N = N_NODES, E = N_EDGES;
    const int NF = N * HID;

    float* p = (float*)d_ws;
    unsigned short* outbb = (unsigned short*)p; p += NF / 2;   // 12.8 MB bf16
    unsigned short* ph    = (unsigned short*)p; p += NF / 2;   // 12.8 MB bf16 row-major
    unsigned short* Wt    = (unsigned short*)p; p += 4 * 16384 / 2;
    float* dnorm = p; p += N;
    float* gemb  = p; p += N_GRAPHS * HID;
    float* projg = p; p += N_GRAPHS * PROJ;
    float* projt = p; p += N_GRAPHS * PROJ;
    // contiguous zero-init region: cnt | cursor | stats4
    int* cnt      = (int*)p; p += N;
    int* cursor   = (int*)p; p += N;
    float* stats4 = p; p += 4 * 256;
    int* rowstart = (int*)p; p += N + 1;
    int* gstart   = (int*)p; p += N_GRAPHS + 1;
    int* bsum     = (int*)p; p += 256;
    int* srcl     = (int*)p; p += E;

    float* outp = (float*)d_out;
    float* o_gproj = outp;
    float* o_tproj = outp + N_GRAPHS * PROJ;
    float* o_glogp = o_tproj + N_GRAPHS * PROJ;
    float* o_tlogp = o_glogp + N_GRAPHS * N_CLS;

    // ---- CSR build + prep ----
    hipMemsetAsync(cnt, 0, (size_t)(2 * N + 4 * 256) * sizeof(int), stream);
    k_deg<<<(E + 255) / 256, 256, 0, stream>>>(ei, cnt, E);
    k_scan1<<<NB_SCAN, 256, 0, stream>>>(cnt, rowstart, dnorm, bsum);
    k_scan2<<<1, 256, 0, stream>>>(bsum);
    k_scan3<<<NB_SCAN, 256, 0, stream>>>(rowstart, bsum);
    k_fill<<<(E + 255) / 256, 256, 0, stream>>>(ei, rowstart, cursor, srcl, E);
    k_prep<<<(4 * 16384 + N + 1 + 255) / 256, 256, 0, stream>>>(gcnW, Wt, batch, gstart);

    // ---- 4 GCN layers (BN of layer l-1 folded into mm of layer l) ----
    for (int l = 0; l < 4; l++) {
        const void* in = (l == 0) ? (const void*)x : (const void*)outbb;
        const float* st = (l == 0) ? nullptr : stats4 + (l - 1) * 256;
        const float* bg = (l == 0) ? nullptr : bng + (size_t)(l - 1) * HID;
        const float* bb = (l == 0) ? nullptr : bnb + (size_t)(l - 1) * HID;
        k_gcn_mm_mfma<<<(N + 63) / 64, 256, 0, stream>>>(in, Wt + (size_t)l * 16384,
                                                         st, bg, bb, dnorm, ph, N);
        k_gather<<<2048, 256, 0, stream>>>((const unsigned long long*)ph, srcl, rowstart,
                                           dnorm, gcnb + (size_t)l * HID, outbb,
                                           stats4 + l * 256, N);
    }

    // ---- segmented mean pool (layer-3 BN folded in-block) ----
    k_pool2<<<N_GRAPHS, 256, 0, stream>>>(outbb, gstart, stats4 + 3 * 256,
                                          bng + 3 * HID, bnb + 3 * HID, gemb);

    // ---- fused heads ----
    k_head1x<<<dim3(64, 4), 256, 0, stream>>>(gemb, textf, gW1, gb1, tW1, tb1, projg, projt);
    k_head2c<<<2 * N_GRAPHS, 256, 0, stream>>>(projg, projt,
                                               gW2, gb2, gg, gbe, gclW, gclb,
                                               tW2, tb2, tg, tbe, tclW, tclb,
                                               o_gproj, o_tproj, o_glogp, o_tlogp);
}

// Round 15
// 639.725 us; speedup vs baseline: 1.2594x; 1.0151x over previous
//
#include <hip/hip_runtime.h>
#include <hip/hip_bf16.h>

// Problem sizes (fixed by reference)
#define N_NODES 50000
#define N_EDGES 800000
#define F_IN    128
#define HID     128
#define PROJ    512
#define N_CLS   32
#define N_GRAPHS 256
#define T_EMB   768
#define NB_SCAN ((N_NODES + 255) / 256)   // 196

typedef __attribute__((ext_vector_type(8))) short bf16x8;
typedef __attribute__((ext_vector_type(4))) float f32x4;

__device__ __forceinline__ float bf2f(unsigned short u) {
    unsigned v = ((unsigned)u) << 16;
    return __uint_as_float(v);
}
__device__ __forceinline__ unsigned short f2us(float v) {
    __hip_bfloat16 b = __float2bfloat16(v);
    union { __hip_bfloat16 b; unsigned short u; } c; c.b = b; return c.u;
}

// ---- degree histogram (int atomics over dst) ----
__global__ void k_deg(const int* __restrict__ ei, int* __restrict__ cnt, int nE) {
    int e = blockIdx.x * 256 + threadIdx.x;
    if (e < nE) atomicAdd(cnt + ei[nE + e], 1);
}

// ---- parallel scan pass 1 ----
__global__ __launch_bounds__(256) void k_scan1(const int* __restrict__ cnt,
    int* __restrict__ rowstart, float* __restrict__ dnorm, int* __restrict__ bsum)
{
    __shared__ int ps[256];
    int t = threadIdx.x;
    int i = blockIdx.x * 256 + t;
    int c = (i < N_NODES) ? cnt[i] : 0;
    if (i < N_NODES) dnorm[i] = rsqrtf((float)c + 1.0f);
    ps[t] = c;
    __syncthreads();
    for (int off = 1; off < 256; off <<= 1) {
        int v = (t >= off) ? ps[t - off] : 0;
        __syncthreads();
        ps[t] += v;
        __syncthreads();
    }
    if (i < N_NODES) rowstart[i] = ps[t] - c;
    if (t == 255) bsum[blockIdx.x] = ps[255];
}

// ---- scan pass 2 ----
__global__ __launch_bounds__(256) void k_scan2(int* __restrict__ bsum) {
    __shared__ int ps[256];
    int t = threadIdx.x;
    int v = (t < NB_SCAN) ? bsum[t] : 0;
    ps[t] = v;
    __syncthreads();
    for (int off = 1; off < 256; off <<= 1) {
        int u = (t >= off) ? ps[t - off] : 0;
        __syncthreads();
        ps[t] += u;
        __syncthreads();
    }
    if (t < NB_SCAN) bsum[t] = ps[t] - v;
}

// ---- scan pass 3 ----
__global__ __launch_bounds__(256) void k_scan3(int* __restrict__ rowstart,
                                               const int* __restrict__ bsum) {
    int i = blockIdx.x * 256 + threadIdx.x;
    if (i < N_NODES) rowstart[i] += bsum[blockIdx.x];
    if (i == 0) rowstart[N_NODES] = N_EDGES;
}

// ---- fill CSR src lists ----
__global__ void k_fill(const int* __restrict__ ei, const int* __restrict__ rowstart,
                       int* __restrict__ cursor, int* __restrict__ srcl, int nE) {
    int e = blockIdx.x * 256 + threadIdx.x;
    if (e >= nE) return;
    int s = ei[e];
    int d = ei[nE + e];
    int pos = rowstart[d] + atomicAdd(cursor + d, 1);
    srcl[pos] = s;
}

// ---- combined prep: weight transpose+bf16 and graph boundaries ----
__global__ void k_prep(const float* __restrict__ W, unsigned short* __restrict__ Wt,
                       const int* __restrict__ batch, int* __restrict__ gstart) {
    int t = blockIdx.x * 256 + threadIdx.x;
    if (t < 4 * 128 * 128) {
        int l = t >> 14;
        int k = (t >> 7) & 127;
        int n = t & 127;
        Wt[(size_t)l * 16384 + n * 128 + k] = f2us(W[(size_t)l * 16384 + k * 128 + n]);
    } else {
        int r = t - 4 * 128 * 128;
        if (r <= N_NODES) {
            int b  = (r < N_NODES) ? batch[r] : N_GRAPHS;
            int bp = (r > 0) ? batch[r - 1] : -1;
            for (int g = bp + 1; g <= b && g <= N_GRAPHS; g++) gstart[g] = r;
        }
    }
}

// ---- GCN matmul via bf16 MFMA; direct global A-loads, BN fold in-register;
// epilogue transposed through LDS (reusing Bs) for coalesced uint4 stores. ----
__global__ __launch_bounds__(256) void k_gcn_mm_mfma(const void* __restrict__ inp,
    const unsigned short* __restrict__ Wt,   // [128 n][128 k] bf16 (n-major)
    const float* __restrict__ stats, const float* __restrict__ bng,
    const float* __restrict__ bnb, const float* __restrict__ dnorm,
    unsigned short* __restrict__ ph, int n)
{
    __shared__ __align__(16) unsigned short Bs[128][136];   // 34.8 KB (reused as C-staging)
    __shared__ float scs[128], shs[128];
    int t = threadIdx.x;
    int row0 = blockIdx.x * 64;

    if (stats && t < 128) {
        float inv_n = 1.0f / (float)N_NODES;
        float mu = stats[t] * inv_n;
        float var = stats[128 + t] * inv_n - mu * mu;
        float rs = rsqrtf(var + 1e-5f);
        float sc = rs * bng[t];
        scs[t] = sc;
        shs[t] = bnb[t] - mu * sc;
    }
#pragma unroll
    for (int i = 0; i < 8; i++) {
        int c = t + i * 256;
        int nn = c >> 4;
        int k8 = (c & 15) * 8;
        *(uint4*)&Bs[nn][k8] = *(const uint4*)(Wt + (size_t)nn * 128 + k8);
    }
    __syncthreads();

    int w = t >> 6, lane = t & 63;
    int m = lane & 15, quad = lane >> 4;
    int arow = row0 + w * 16 + m;        // this lane's A row
    bool rowok = arow < n;

    // load A fragments for all 4 k-chunks (16 B each, aligned)
    bf16x8 afrag[4];
    if (!stats) {
        const float* inf = (const float*)inp;
#pragma unroll
        for (int ki = 0; ki < 4; ki++) {
            int k8 = ki * 32 + quad * 8;
            float4 v0 = make_float4(0.f, 0.f, 0.f, 0.f);
            float4 v1 = make_float4(0.f, 0.f, 0.f, 0.f);
            if (rowok) {
                v0 = *(const float4*)(inf + (size_t)arow * 128 + k8);
                v1 = *(const float4*)(inf + (size_t)arow * 128 + k8 + 4);
            }
            union { unsigned short u[8]; bf16x8 v; } pk;
            pk.u[0] = f2us(v0.x); pk.u[1] = f2us(v0.y); pk.u[2] = f2us(v0.z); pk.u[3] = f2us(v0.w);
            pk.u[4] = f2us(v1.x); pk.u[5] = f2us(v1.y); pk.u[6] = f2us(v1.z); pk.u[7] = f2us(v1.w);
            afrag[ki] = pk.v;
        }
    } else {
        const unsigned short* inb = (const unsigned short*)inp;
#pragma unroll
        for (int ki = 0; ki < 4; ki++) {
            int k8 = ki * 32 + quad * 8;
            uint4 raw = make_uint4(0, 0, 0, 0);
            if (rowok) raw = *(const uint4*)(inb + (size_t)arow * 128 + k8);
            unsigned rr[4] = { raw.x, raw.y, raw.z, raw.w };
            union { unsigned short u[8]; bf16x8 v; } pk;
#pragma unroll
            for (int j = 0; j < 4; j++) {
                int f0 = k8 + 2 * j, f1 = k8 + 2 * j + 1;
                float a0 = bf2f((unsigned short)rr[j]) * scs[f0] + shs[f0];
                float a1 = bf2f((unsigned short)(rr[j] >> 16)) * scs[f1] + shs[f1];
                pk.u[2 * j] = f2us(a0);
                pk.u[2 * j + 1] = f2us(a1);
            }
            afrag[ki] = pk.v;
        }
    }

    f32x4 acc[8];
#pragma unroll
    for (int nt = 0; nt < 8; nt++) acc[nt] = (f32x4){0.f, 0.f, 0.f, 0.f};
#pragma unroll
    for (int ki = 0; ki < 4; ki++) {
#pragma unroll
        for (int nt = 0; nt < 8; nt++) {
            bf16x8 b = *(const bf16x8*)&Bs[nt * 16 + m][ki * 32 + quad * 8];
            acc[nt] = __builtin_amdgcn_mfma_f32_16x16x32_bf16(afrag[ki], b, acc[nt], 0, 0, 0);
        }
    }

    float dn[4];
#pragma unroll
    for (int reg = 0; reg < 4; reg++) {
        int gr = row0 + w * 16 + quad * 4 + reg;
        dn[reg] = (gr < n) ? dnorm[gr] : 0.f;
    }

    // ---- epilogue: transpose C through LDS (reuse Bs) for coalesced stores ----
    __syncthreads();   // all waves finished reading Bs
#pragma unroll
    for (int nt = 0; nt < 8; nt++) {
#pragma unroll
        for (int reg = 0; reg < 4; reg++) {
            Bs[w * 16 + quad * 4 + reg][nt * 16 + m] = f2us(acc[nt][reg] * dn[reg]);
        }
    }
    __syncthreads();
#pragma unroll
    for (int i = 0; i < 4; i++) {
        int idx = t + i * 256;           // 0..1023
        int r = idx >> 4;                // 0..63
        int c8 = (idx & 15) * 8;         // 0..120
        int gr = row0 + r;
        if (gr < n) *(uint4*)(ph + (size_t)gr * 128 + c8) = *(const uint4*)&Bs[r][c8];
    }
}

// ---- pair-gather (round-11 form): one wave per dst row; bf16 output ----
__global__ __launch_bounds__(256) void k_gather(const unsigned long long* __restrict__ ph64,
    const int* __restrict__ srcl, const int* __restrict__ rowstart,
    const float* __restrict__ dnorm, const float* __restrict__ bias,
    unsigned short* __restrict__ outbb, float* __restrict__ stats, int n)
{
    const int EMAX = N_EDGES - 1;
    int t = threadIdx.x;
    int lane = t & 63;
    int w = t >> 6;
    int hl = lane >> 5;
    int l32 = lane & 31;
    float4 bi4 = *(const float4*)&bias[l32 * 4];
    float4 s4 = make_float4(0.f, 0.f, 0.f, 0.f);
    float4 q4 = make_float4(0.f, 0.f, 0.f, 0.f);

    for (int r = blockIdx.x * 4 + w; r < n; r += gridDim.x * 4) {
        int start = rowstart[r], end = rowstart[r + 1];
        int deg = end - start;
        int len = deg + 1;
        float a0 = 0.f, a1 = 0.f, a2 = 0.f, a3 = 0.f;
        int j = 0;
        for (; 2 * (j + 4) <= len; j += 4) {
#pragma unroll
            for (int u = 0; u < 4; u++) {
                int i = 2 * (j + u) + hl;
                int sl = srcl[min(start + i, EMAX)];
                int s = (i < deg) ? sl : r;
                unsigned long long uv = ph64[(size_t)s * 32 + l32];
                unsigned lo = (unsigned)uv, hi = (unsigned)(uv >> 32);
                a0 += bf2f((unsigned short)lo);
                a1 += bf2f((unsigned short)(lo >> 16));
                a2 += bf2f((unsigned short)hi);
                a3 += bf2f((unsigned short)(hi >> 16));
            }
        }
        for (; 2 * j < len; j++) {
            int i = 2 * j + hl;
            int sl = srcl[min(start + i, EMAX)];
            int s = (i < deg) ? sl : r;
            unsigned long long uv = ph64[(size_t)s * 32 + l32];
            float w0 = (i < len) ? 1.f : 0.f;
            unsigned lo = (unsigned)uv, hi = (unsigned)(uv >> 32);
            a0 += w0 * bf2f((unsigned short)lo);
            a1 += w0 * bf2f((unsigned short)(lo >> 16));
            a2 += w0 * bf2f((unsigned short)hi);
            a3 += w0 * bf2f((unsigned short)(hi >> 16));
        }
        a0 += __shfl_xor(a0, 32, 64);
        a1 += __shfl_xor(a1, 32, 64);
        a2 += __shfl_xor(a2, 32, 64);
        a3 += __shfl_xor(a3, 32, 64);
        if (hl == 0) {
            float dn = dnorm[r];
            float v0 = a0 * dn + bi4.x;
            float v1 = a1 * dn + bi4.y;
            float v2 = a2 * dn + bi4.z;
            float v3 = a3 * dn + bi4.w;
            v0 = v0 > 0.f ? v0 : 0.01f * v0;
            v1 = v1 > 0.f ? v1 : 0.01f * v1;
            v2 = v2 > 0.f ? v2 : 0.01f * v2;
            v3 = v3 > 0.f ? v3 : 0.01f * v3;
            ushort4 ov;
            ov.x = f2us(v0); ov.y = f2us(v1); ov.z = f2us(v2); ov.w = f2us(v3);
            *(ushort4*)(outbb + (size_t)r * 128 + l32 * 4) = ov;
            s4.x += v0; s4.y += v1; s4.z += v2; s4.w += v3;
            q4.x += v0 * v0; q4.y += v1 * v1; q4.z += v2 * v2; q4.w += v3 * v3;
        }
    }
    __shared__ float sb[4][32][4], sq[4][32][4];
    if (hl == 0) {
        *(float4*)&sb[w][l32][0] = s4;
        *(float4*)&sq[w][l32][0] = q4;
    }
    __syncthreads();
    if (t < 128) {
        int f = t, l = f >> 2, c = f & 3;
        float ss = (sb[0][l][c] + sb[1][l][c]) + (sb[2][l][c] + sb[3][l][c]);
        float qq = (sq[0][l][c] + sq[1][l][c]) + (sq[2][l][c] + sq[3][l][c]);
        atomicAdd(&stats[f], ss);
        atomicAdd(&stats[128 + f], qq);
    }
}

// ---- segmented mean pool (bf16 input); BN scale/shift computed in-block ----
__global__ __launch_bounds__(256) void k_pool2(const unsigned short* __restrict__ outbb,
    const int* __restrict__ gstart, const float* __restrict__ stats,
    const float* __restrict__ bng, const float* __restrict__ bnb,
    float* __restrict__ gemb)
{
    __shared__ float scs[128], shs[128];
    int g = blockIdx.x;
    int t = threadIdx.x;
    if (t < 128) {
        float inv_n = 1.0f / (float)N_NODES;
        float mu = stats[t] * inv_n;
        float var = stats[128 + t] * inv_n - mu * mu;
        float rs = rsqrtf(var + 1e-5f);
        float sc = rs * bng[t];
        scs[t] = sc;
        shs[t] = bnb[t] - mu * sc;
    }
    __syncthreads();
    int f = t & 127;
    int half = t >> 7;
    int start = gstart[g], end = gstart[g + 1];
    int cnt = end - start;
    float s0 = 0.f, s1 = 0.f, s2 = 0.f, s3 = 0.f;
    int r = start + half;
    for (; r + 6 < end; r += 8) {
        s0 += bf2f(outbb[(size_t)(r    ) * 128 + f]);
        s1 += bf2f(outbb[(size_t)(r + 2) * 128 + f]);
        s2 += bf2f(outbb[(size_t)(r + 4) * 128 + f]);
        s3 += bf2f(outbb[(size_t)(r + 6) * 128 + f]);
    }
    for (; r < end; r += 2) s0 += bf2f(outbb[(size_t)r * 128 + f]);
    float sum = (s0 + s1) + (s2 + s3);
    __shared__ float sb[256];
    sb[t] = sum;
    __syncthreads();
    if (t < 128) {
        float tot = sb[t] + sb[t + 128];
        float v = (cnt > 0) ? (tot / (float)cnt) * scs[f] + shs[f] : 0.f;
        gemb[(size_t)g * 128 + f] = v;
    }
}

// ---- fused head layer 1 for both heads ----
__global__ __launch_bounds__(256) void k_head1x(const float* __restrict__ gemb,
    const float* __restrict__ textf,
    const float* __restrict__ gW1, const float* __restrict__ gb1,
    const float* __restrict__ tW1, const float* __restrict__ tb1,
    float* __restrict__ projg, float* __restrict__ projt)
{
    __shared__ float ins[8][768];
    int bx = blockIdx.x;
    int chunk = blockIdx.y;
    int isT = bx >= 32;
    int rb = isT ? bx - 32 : bx;
    const float* in = isT ? textf : gemb;
    int K = isT ? T_EMB : HID;
    const float* W = isT ? tW1 : gW1;
    const float* b = isT ? tb1 : gb1;
    float* outp = isT ? projt : projg;

    int t = threadIdx.x;
    int tot = 8 * K;
    for (int l = t; l < tot; l += 256) {
        int r = l / K, k = l - r * K;
        ins[r][k] = in[(size_t)(rb * 8 + r) * K + k];
    }
    __syncthreads();
    int col = chunk * 128 + (t & 127);
    int rg = t >> 7;
    float acc[4] = { 0.f, 0.f, 0.f, 0.f };
    for (int k = 0; k < K; k++) {
        float w = W[(size_t)k * 512 + col];
#pragma unroll
        for (int i = 0; i < 4; i++) acc[i] += ins[rg * 4 + i][k] * w;
    }
    float bias = b[col];
#pragma unroll
    for (int i = 0; i < 4; i++) {
        int row = rb * 8 + rg * 4 + i;
        outp[(size_t)row * 512 + col] = acc[i] + bias;
    }
}

// ---- fused head2 + LayerNorm + classifier + log_softmax, both heads ----
__global__ __launch_bounds__(256) void k_head2c(
    const float* __restrict__ projg, const float* __restrict__ projt,
    const float* __restrict__ gW2, const float* __restrict__ gb2,
    const float* __restrict__ gg, const float* __restrict__ gbe,
    const float* __restrict__ gclW, const float* __restrict__ gclb,
    const float* __restrict__ tW2, const float* __restrict__ tb2,
    const float* __restrict__ tg, const float* __restrict__ tbe,
    const float* __restrict__ tclW, const float* __restrict__ tclb,
    float* __restrict__ o_gproj, float* __restrict__ o_tproj,
    float* __restrict__ o_glogp, float* __restrict__ o_tlogp)
{
    __shared__ float prow[512], grow[512], onorm[512], red[256];
    __shared__ float part[8][32];
    __shared__ float logits[32];
    __shared__ float mred, lred;
    int bx = blockIdx.x;
    int isT = bx >= N_GRAPHS;
    int row = isT ? bx - N_GRAPHS : bx;
    const float* proj = isT ? projt : projg;
    const float* W2 = isT ? tW2 : gW2;
    const float* b2 = isT ? tb2 : gb2;
    const float* g  = isT ? tg  : gg;
    const float* be = isT ? tbe : gbe;
    const float* Wc = isT ? tclW : gclW;
    const float* bc = isT ? tclb : gclb;
    float* oproj = isT ? o_tproj : o_gproj;
    float* ologp = isT ? o_tlogp : o_glogp;

    int t = threadIdx.x;
    for (int c = t; c < 512; c += 256) {
        float p = proj[(size_t)row * 512 + c];
        prow[c] = p;
        grow[c] = 0.5f * p * (1.0f + erff(p * 0.70710678118f));
    }
    __syncthreads();
    float a0 = 0.f, a1 = 0.f;
    int c0 = t, c1 = t + 256;
    for (int k = 0; k < 512; k++) {
        float gk = grow[k];
        a0 += gk * W2[(size_t)k * 512 + c0];
        a1 += gk * W2[(size_t)k * 512 + c1];
    }
    float h0 = a0 + b2[c0] + prow[c0];
    float h1 = a1 + b2[c1] + prow[c1];
    red[t] = h0 + h1;
    __syncthreads();
    for (int s = 128; s > 0; s >>= 1) { if (t < s) red[t] += red[t + s]; __syncthreads(); }
    float mu = red[0] * (1.0f / 512.0f);
    __syncthreads();
    float d0 = h0 - mu, d1 = h1 - mu;
    red[t] = d0 * d0 + d1 * d1;
    __syncthreads();
    for (int s = 128; s > 0; s >>= 1) { if (t < s) red[t] += red[t + s]; __syncthreads(); }
    float rs = rsqrtf(red[0] * (1.0f / 512.0f) + 1e-5f);
    float o0 = d0 * rs * g[c0] + be[c0];
    float o1 = d1 * rs * g[c1] + be[c1];
    onorm[c0] = o0;
    onorm[c1] = o1;
    oproj[(size_t)row * 512 + c0] = o0;
    oproj[(size_t)row * 512 + c1] = o1;
    __syncthreads();

    int c = t & 31, seg = t >> 5;
    float p = 0.f;
    for (int k = seg * 64; k < seg * 64 + 64; k++)
        p += onorm[k] * Wc[(size_t)k * 32 + c];
    part[seg][c] = p;
    __syncthreads();
    if (t < 32) {
        float l = bc[t];
#pragma unroll
        for (int s = 0; s < 8; s++) l += part[s][t];
        logits[t] = l;
    }
    __syncthreads();
    if (t == 0) {
        float m = logits[0];
        for (int i = 1; i < 32; i++) m = fmaxf(m, logits[i]);
        float sum = 0.f;
        for (int i = 0; i < 32; i++) sum += expf(logits[i] - m);
        mred = m; lred = logf(sum);
    }
    __syncthreads();
    if (t < 32) ologp[(size_t)row * 32 + t] = logits[t] - mred - lred;
}

extern "C" void kernel_launch(void* const* d_in, const int* in_sizes, int n_in,
                              void* d_out, int out_size, void* d_ws, size_t ws_size,
                              hipStream_t stream) {
    const float* x     = (const float*)d_in[0];
    const int*   ei    = (const int*)d_in[1];
    const int*   batch = (const int*)d_in[2];
    const float* textf = (const float*)d_in[3];
    const float* gcnW  = (const float*)d_in[4];
    const float* gcnb  = (const float*)d_in[5];
    const float* bng   = (const float*)d_in[6];
    const float* bnb   = (const float*)d_in[7];
    const float* gW1   = (const float*)d_in[8];
    const float* gb1   = (const float*)d_in[9];
    const float* gW2   = (const float*)d_in[10];
    const float* gb2   = (const float*)d_in[11];
    const float* gg    = (const float*)d_in[12];
    const float* gbe   = (const float*)d_in[13];
    const float* gclW  = (const float*)d_in[14];
    const float* gclb  = (const float*)d_in[15];
    const float* tW1   = (const float*)d_in[16];
    const float* tb1   = (const float*)d_in[17];
    const float* tW2   = (const float*)d_in[18];
    const float* tb2   = (const float*)d_in[19];
    const float* tg    = (const float*)d_in[20];
    const float* tbe   = (const float*)d_in[21];
    const float* tclW  = (const float*)d_in[22];
    const float* tclb  = (const float*)d_in[23];

    const int N = N_NODES, E = N_EDGES;
    const int NF = N * HID;

    float* p = (float*)d_ws;
    unsigned short* outbb = (unsigned short*)p; p += NF / 2;   // 12.8 MB bf16
    unsigned short* ph    = (unsigned short*)p; p += NF / 2;   // 12.8 MB bf16 row-major
    unsigned short* Wt    = (unsigned short*)p; p += 4 * 16384 / 2;
    float* dnorm = p; p += N;
    float* gemb  = p; p += N_GRAPHS * HID;
    float* projg = p; p += N_GRAPHS * PROJ;
    float* projt = p; p += N_GRAPHS * PROJ;
    // contiguous zero-init region: cnt | cursor | stats4
    int* cnt      = (int*)p; p += N;
    int* cursor   = (int*)p; p += N;
    float* stats4 = p; p += 4 * 256;
    int* rowstart = (int*)p; p += N + 1;
    int* gstart   = (int*)p; p += N_GRAPHS + 1;
    int* bsum     = (int*)p; p += 256;
    int* srcl     = (int*)p; p += E;

    float* outp = (float*)d_out;
    float* o_gproj = outp;
    float* o_tproj = outp + N_GRAPHS * PROJ;
    float* o_glogp = o_tproj + N_GRAPHS * PROJ;
    float* o_tlogp = o_glogp + N_GRAPHS * N_CLS;

    // ---- CSR build + prep ----
    hipMemsetAsync(cnt, 0, (size_t)(2 * N + 4 * 256) * sizeof(int), stream);
    k_deg<<<(E + 255) / 256, 256, 0, stream>>>(ei, cnt, E);
    k_scan1<<<NB_SCAN, 256, 0, stream>>>(cnt, rowstart, dnorm, bsum);
    k_scan2<<<1, 256, 0, stream>>>(bsum);
    k_scan3<<<NB_SCAN, 256, 0, stream>>>(rowstart, bsum);
    k_fill<<<(E + 255) / 256, 256, 0, stream>>>(ei, rowstart, cursor, srcl, E);
    k_prep<<<(4 * 16384 + N + 1 + 255) / 256, 256, 0, stream>>>(gcnW, Wt, batch, gstart);

    // ---- 4 GCN layers (BN of layer l-1 folded into mm of layer l) ----
    for (int l = 0; l < 4; l++) {
        const void* in = (l == 0) ? (const void*)x : (const void*)outbb;
        const float* st = (l == 0) ? nullptr : stats4 + (l - 1) * 256;
        const float* bg = (l == 0) ? nullptr : bng + (size_t)(l - 1) * HID;
        const float* bb = (l == 0) ? nullptr : bnb + (size_t)(l - 1) * HID;
        k_gcn_mm_mfma<<<(N + 63) / 64, 256, 0, stream>>>(in, Wt + (size_t)l * 16384,
                                                         st, bg, bb, dnorm, ph, N);
        k_gather<<<2048, 256, 0, stream>>>((const unsigned long long*)ph, srcl, rowstart,
                                           dnorm, gcnb + (size_t)l * HID, outbb,
                                           stats4 + l * 256, N);
    }

    // ---- segmented mean pool (layer-3 BN folded in-block) ----
    k_pool2<<<N_GRAPHS, 256, 0, stream>>>(outbb, gstart, stats4 + 3 * 256,
                                          bng + 3 * HID, bnb + 3 * HID, gemb);

    // ---- fused heads ----
    k_head1x<<<dim3(64, 4), 256, 0, stream>>>(gemb, textf, gW1, gb1, tW1, tb1, projg, projt);
    k_head2c<<<2 * N_GRAPHS, 256, 0, stream>>>(projg, projt,
                                               gW2, gb2, gg, gbe, gclW, gclb,
                                               tW2, tb2, tg, tbe, tclW, tclb,
                                               o_gproj, o_tproj, o_glogp, o_tlogp);
}